// Round 7
// baseline (229.621 us; speedup 1.0000x reference)
//
#include <hip/hip_runtime.h>
#include <math.h>

#define THREADS 256
#define NBLOCKS 2048   // 8 blocks/CU x 256 CU = max co-resident at 256 thr/block

// ===== DIAGNOSTIC AMPLIFIER (round 7 resubmit; round-6 bench was an infra
// failure — "container failed twice" — with no counters returned) =====
// Round-5 persistent kernel, body byte-identical, compute repeated 8x with
// asm keep-alives (same technique as round 2, which faithfully matched the
// marginal-launch measurement). Purpose: first-ever counters for the
// persistent structure -- OccupancyPercent (did persistence fix residency?),
// VALUBusy, VGPR_Count, and dur/rep (is T_k really ~29us, or harness-masked?).
#define REP 8

// 32 magnitude patterns of the D4 codebook, 2-bit codes per coordinate:
// c in {0,1,2}  =>  |g_i| = 0.5 + c.   mc = c0 | c1<<2 | c2<<4 | c3<<6
// Pattern order is exactly the reference's i8 = 0..31 enumeration.
// Score identity: s_p = (A-1) + sum_{c_i=1}(2a_i-2) + sum_{c_i=2}(4a_i-6).
#define MCP_LIST \
  0x00, 0x55, 0x50, 0x05, 0x44, 0x11, 0x14, 0x41, \
  0x01, 0x04, 0x10, 0x40, 0x54, 0x51, 0x45, 0x15, \
  0x02, 0x08, 0x20, 0x80, 0x09, 0x06, 0x12, 0x42, \
  0x21, 0x24, 0x18, 0x48, 0x81, 0x84, 0x90, 0x60

constexpr unsigned h_MCP[32] = { MCP_LIST };   // compile-time folded copy

// Same table packed 8 patterns per uint64 (byte p&7 of word p>>3), so the
// winner's byte is a branch-free select tree + 64-bit shift (no LDS/memory).
#define PK0 0x4114114405505500ull
#define PK1 0x1545515440100401ull
#define PK2 0x4212060980200802ull
#define PK3 0x6090848148182421ull

// Rare (~2e-4): bit-exact emulation of the numpy reference.
// Sequential f32 dot (no FMA), 2*dot - gn, first-wins argmax.
__device__ __noinline__ void exact_scan(float fx0, float fx1, float fx2, float fx3,
                                        const float4* __restrict__ sgrid,
                                        const float* __restrict__ sgn,
                                        float4* g, float* fidx)
{
    float bexact = -INFINITY;
    int bk = 0;
    for (int k = 0; k < 256; ++k) {
        const float4 gk = sgrid[k];
        float d = __fmul_rn(fx0, gk.x);
        d = __fadd_rn(d, __fmul_rn(fx1, gk.y));
        d = __fadd_rn(d, __fmul_rn(fx2, gk.z));
        d = __fadd_rn(d, __fmul_rn(fx3, gk.w));
        const float sc = __fsub_rn(__fmul_rn(2.0f, d), sgn[k]);
        if (sc > bexact) { bexact = sc; bk = k; }
    }
    *g = sgrid[bk];
    *fidx = (float)bk;
}

__global__ __launch_bounds__(THREADS, 8)
void d4_fused_kernel(const float* __restrict__ X,
                     const float* __restrict__ grid,
                     const float* __restrict__ gnorm,
                     float* __restrict__ out, int n)
{
    // Stage codebook once per PERSISTENT block (amortized over ~512 vectors).
    __shared__ float4 sgrid[256];
    __shared__ float  sgn[256];
    sgrid[threadIdx.x] = reinterpret_cast<const float4*>(grid)[threadIdx.x];
    sgn[threadIdx.x]   = gnorm[threadIdx.x];
    __syncthreads();   // before any early-exit (whole block reaches this)

    const int stride = gridDim.x * blockDim.x;
    int idx = blockIdx.x * blockDim.x + threadIdx.x;
    if (idx >= n) return;

    const float4* __restrict__ X4 = reinterpret_cast<const float4*>(X);
    float4* __restrict__ O4 = reinterpret_cast<float4*>(out);
    float* __restrict__ Oi = out + (size_t)4 * (size_t)n;

    float4 xv = X4[idx];
    for (;;) {
        // ---- prefetch next iteration's vector (hides HBM latency) ----
        const int nidx = idx + stride;
        const bool hasnext = (nidx < n);
        const float4 xn = hasnext ? X4[nidx] : xv;

        float4 g;
        float fidx;

#pragma unroll 1
        for (int rep = 0; rep < REP; ++rep) {
            float fx0 = xv.x, fx1 = xv.y, fx2 = xv.z, fx3 = xv.w;
            // opaque copy: forces full recompute each rep; loads stay hoisted
            asm volatile("" : "+v"(fx0), "+v"(fx1), "+v"(fx2), "+v"(fx3));

            const float a0 = fabsf(fx0), a1 = fabsf(fx1), a2 = fabsf(fx2), a3 = fabsf(fx3);
            // exact: u = 2a, v = 4a
            const float r0 = (a0 + a0) - 2.f, r1 = (a1 + a1) - 2.f;
            const float r2 = (a2 + a2) - 2.f, r3 = (a3 + a3) - 2.f;
            const float z0 = (a0 + a0 + a0 + a0) - 6.f, z1 = (a1 + a1 + a1 + a1) - 6.f;
            const float z2 = (a2 + a2 + a2 + a2) - 6.f, z3 = (a3 + a3 + a3 + a3) - 6.f;
            const float A = (a0 + a1) + (a2 + a3);
            const float base = A - 1.f;

            // magnitude-weighted "flip costs" m_i * a_i for the 3 levels
            const float h0 = 0.5f * a0, h1 = 0.5f * a1, h2 = 0.5f * a2, h3 = 0.5f * a3;
            const float t0 = h0 + a0, t1 = h1 + a1, t2 = h2 + a2, t3 = h3 + a3;  // 1.5a
            const float w0 = t0 + a0, w1 = t1 + a1, w2 = t2 + a2, w3 = t3 + a3;  // 2.5a

            const int s0 = (fx0 < 0.f) ? 1 : 0, s1 = (fx1 < 0.f) ? 1 : 0;
            const int s2 = (fx2 < 0.f) ? 1 : 0, s3 = (fx3 < 0.f) ? 1 : 0;
            const int qp = (s0 + s1 + s2 + s3) & 1;   // parity of # negative coords

            // parity-penalty factors: penalty applies when rp != qp
            const float nA = qp ? -4.f : 0.f;
            const float nB = qp ? 0.f : -4.f;

            float best = -1e30f, second = -1e30f;
            int bi = 0;
#pragma unroll
            for (int p = 0; p < 32; ++p) {
                const unsigned mcp = h_MCP[p];
                const int c0 = mcp & 3, c1 = (mcp >> 2) & 3, c2 = (mcp >> 4) & 3, c3 = (mcp >> 6) & 3;

                float s = base;
                if (c0 == 1) s += r0; else if (c0 == 2) s += z0;
                if (c1 == 1) s += r1; else if (c1 == 2) s += z1;
                if (c2 == 1) s += r2; else if (c2 == 2) s += z2;
                if (c3 == 1) s += r3; else if (c3 == 2) s += z3;

                // compile-time register picks (free)
                const float q0 = (c0 == 0) ? h0 : ((c0 == 1) ? t0 : w0);
                const float q1 = (c1 == 0) ? h1 : ((c1 == 1) ? t1 : w1);
                const float q2 = (c2 == 0) ? h2 : ((c2 == 1) ? t2 : w2);
                const float q3 = (c3 == 0) ? h3 : ((c3 == 1) ? t3 : w3);
                // left-leaning chain fuses to v_min3 + v_min (2 ops vs 3)
                const float minp = fminf(fminf(fminf(q0, q1), q2), q3);

                const int rp = (c0 + c1 + c2 + c3) & 1;    // compile-time
                const float eff = fmaf(minp, rp ? nB : nA, s);

                // branch-free top-2 + index (exact; first-wins on ties via strict >)
                // med3(best, second, eff) == new runner-up given second <= best
                const bool gt = eff > best;
                bi = gt ? p : bi;
                second = __builtin_amdgcn_fmed3f(best, second, eff);
                best = fmaxf(best, eff);
            }

            // ---- winner's magnitude byte: branch-free packed-table select ----
            const unsigned long long w01 = (bi & 8) ? PK1 : PK0;
            const unsigned long long w23 = (bi & 8) ? PK3 : PK2;
            const unsigned long long wsel = (bi & 16) ? w23 : w01;
            const unsigned mc = (unsigned)(wsel >> ((bi & 7) * 8)) & 0xFFu;

            const int c0 = mc & 3, c1 = (mc >> 2) & 3, c2 = (mc >> 4) & 3, c3 = (mc >> 6) & 3;
            const int rp = (c0 + c1 + c2 + c3) & 1;
            const bool flip = (rp != qp);

            const float p0 = (c0 == 0) ? h0 : ((c0 == 1) ? t0 : w0);
            const float p1 = (c1 == 0) ? h1 : ((c1 == 1) ? t1 : w1);
            const float p2 = (c2 == 0) ? h2 : ((c2 == 1) ? t2 : w2);
            const float p3 = (c3 == 0) ? h3 : ((c3 == 1) ? t3 : w3);
            int f = 0; float mp = p0;
            if (p1 < mp) { mp = p1; f = 1; }
            if (p2 < mp) { mp = p2; f = 2; }
            if (p3 < mp) { mp = p3; f = 3; }

            // two smallest of {p0..p3} (for the within-pattern runner-up bound)
            const float m01 = fminf(p0, p1), M01 = fmaxf(p0, p1);
            const float m23 = fminf(p2, p3), M23 = fmaxf(p2, p3);
            const float q1v = fminf(m01, m23);
            const float q2v = fminf(fmaxf(m01, m23), fminf(M01, M23));

            // runner-up within the winning pattern:
            //  parity mismatch: second-best single flip  -> cost gap 4*(q2-q1)
            //  parity match:    cheapest double flip     -> cost 4*(q1+q2)
            const float within = flip ? 4.f * (q2v - q1v) : 4.f * (q1v + q2v);
            const float gap = fminf(best - second, within);
            // covers worst-case f32 rounding of BOTH my scores and the numpy
            // reference's (each <= ~7e-7*(5A+27)); >2x safety margin
            const float delta = 8e-6f * (A + 6.f);

            const bool n0 = ((s0 != 0) != (flip && f == 0));
            const bool n1 = ((s1 != 0) != (flip && f == 1));
            const bool n2 = ((s2 != 0) != (flip && f == 2));
            const bool n3 = ((s3 != 0) != (flip && f == 3));

            const float m0 = 0.5f + (float)c0, m1 = 0.5f + (float)c1;
            const float m2 = 0.5f + (float)c2, m3 = 0.5f + (float)c3;
            g.x = n0 ? -m0 : m0;
            g.y = n1 ? -m1 : m1;
            g.z = n2 ? -m2 : m2;
            g.w = n3 ? -m3 : m3;

            // invert _code3_signs: b7=sign(g0), b6=sign(g1)^b7, b5=sign(g2)^b7
            const int b7 = n0 ? 1 : 0;
            const int b6 = (n1 ? 1 : 0) ^ b7;
            const int b5 = (n2 ? 1 : 0) ^ b7;
            fidx = (float)(bi | (b5 << 5) | (b6 << 6) | (b7 << 7));

            if (gap < delta) {
                exact_scan(fx0, fx1, fx2, fx3, sgrid, sgn, &g, &fidx);
            }

            // consume results each rep so reps can't be dead-code-eliminated
            asm volatile("" : "+v"(g.x), "+v"(g.y), "+v"(g.z), "+v"(g.w), "+v"(fidx));
        }

        O4[idx] = g;              // output 0
        Oi[idx] = fidx;           // output 1

        if (!hasnext) break;
        idx = nidx;
        xv = xn;
    }
}

extern "C" void kernel_launch(void* const* d_in, const int* in_sizes, int n_in,
                              void* d_out, int out_size, void* d_ws, size_t ws_size,
                              hipStream_t stream)
{
    const float* X = (const float*)d_in[0];
    const float* grid = (const float*)d_in[1];
    const float* gnorm = (const float*)d_in[2];
    float* out = (float*)d_out;
    const int n = in_sizes[0] / 4;
    int blocks = (n + THREADS - 1) / THREADS;
    if (blocks > NBLOCKS) blocks = NBLOCKS;   // persistent grid, grid-stride loop
    hipLaunchKernelGGL(d4_fused_kernel, dim3(blocks), dim3(THREADS), 0, stream,
                       X, grid, gnorm, out, n);
}

// Round 8
// 89.994 us; speedup vs baseline: 2.5515x; 2.5515x over previous
//
#include <hip/hip_runtime.h>
#include <math.h>

#define THREADS 256

// ============================================================================
// Sorted-axis direct decode of the D4 codebook (round 8 rewrite).
//
// The 256-entry codebook = 32 magnitude patterns x 8 sign classes (even minus-
// parity). The magnitude-pattern set is PERMUTATION-INVARIANT:
//   {all 0/1 subsets (16)} u {one 2 (4)} u {one 2 + one 1 (12)}.
// After sorting a=|x| DESC (v0>=v1>=v2>=v3, perm p0..p3), the argmax over all
// 32 patterns is always one of SEVEN candidates (ties -> slow path):
//   id0..id4: ones at sorted prefix of length k=id (score base + sum r_i)
//   id5: 2 @ sorted pos0          id6: 2 @ pos0, 1 @ pos1
// Dominance: any excluded pattern is <= its same-parity candidate minus
// 2*dadj_min (min adjacent sorted gap): per-fixed-k the prefix maximizes the
// score sum (top-k values), and every candidate's parity penalty equals the
// GLOBAL minimum flip cost 4*0.5*v3 = 2*v3 (all flip costs (0.5+c)*a_i >=
// 0.5*v3), so pen_excluded >= pen_candidate. Hence certified runner-up bound:
//   second_true <= max(cand_second, best - 2*dadj_min).
// Sign fix on parity mismatch always flips coordinate perm[3] (cost 2*v3;
// 6*v3 for id4 whose min flip is 1.5*v3). Flip-coord ties are caught by the
// 'within' term (4*(q2-q1) -> 0); sort ties by dadj_min -> 0. All near-ties
// route to the bit-exact slow path exactly as in the verified enumeration
// kernel (same delta = 8e-6*(A+6): my chains here are <= 8 rounding steps on
// the same magnitude scale, within the established per-side bound).
// ============================================================================

// Rare (~3e-4): bit-exact emulation of the numpy reference.
// Sequential f32 dot (no FMA), 2*dot - gn, first-wins argmax.
// __noinline__ keeps the 256-iter body off the fast path's fetch stream.
__device__ __noinline__ void exact_scan(float fx0, float fx1, float fx2, float fx3,
                                        const float4* __restrict__ sgrid,
                                        const float* __restrict__ sgn,
                                        float4* g, float* fidx)
{
    float bexact = -INFINITY;
    int bk = 0;
    for (int k = 0; k < 256; ++k) {
        const float4 gk = sgrid[k];
        float d = __fmul_rn(fx0, gk.x);
        d = __fadd_rn(d, __fmul_rn(fx1, gk.y));
        d = __fadd_rn(d, __fmul_rn(fx2, gk.z));
        d = __fadd_rn(d, __fmul_rn(fx3, gk.w));
        const float sc = __fsub_rn(__fmul_rn(2.0f, d), sgn[k]);
        if (sc > bexact) { bexact = sc; bk = k; }
    }
    *g = sgrid[bk];
    *fidx = (float)bk;
}

__global__ __launch_bounds__(THREADS)
void d4_fused_kernel(const float* __restrict__ X,
                     const float* __restrict__ grid,
                     const float* __restrict__ gnorm,
                     float* __restrict__ out, int n)
{
    // Stage codebook for the (rare) exact slow path; broadcast reads later.
    __shared__ float4 sgrid[256];
    __shared__ float  sgn[256];
    sgrid[threadIdx.x] = reinterpret_cast<const float4*>(grid)[threadIdx.x];
    sgn[threadIdx.x]   = gnorm[threadIdx.x];
    __syncthreads();

    const int i = blockIdx.x * blockDim.x + threadIdx.x;
    if (i >= n) return;

    const float4 xv = reinterpret_cast<const float4*>(X)[i];
    const float fx0 = xv.x, fx1 = xv.y, fx2 = xv.z, fx3 = xv.w;

    const float a0 = fabsf(fx0), a1 = fabsf(fx1), a2 = fabsf(fx2), a3 = fabsf(fx3);
    const int sg0 = (fx0 < 0.f) ? 1 : 0, sg1 = (fx1 < 0.f) ? 1 : 0;
    const int sg2 = (fx2 < 0.f) ? 1 : 0, sg3 = (fx3 < 0.f) ? 1 : 0;
    const int qp = (sg0 + sg1 + sg2 + sg3) & 1;   // minus-parity of optimal signs

    // ---- sort DESC with permutation (5 compare-exchanges) ----
    float v0 = a0, v1 = a1, v2 = a2, v3 = a3;
    int p0 = 0, p1 = 1, p2 = 2, p3 = 3;
#define CSW(x, y, ix, iy) { const bool lt_ = (x) < (y); \
    const float tf_ = x; x = lt_ ? y : x; y = lt_ ? tf_ : y; \
    const int ti_ = ix; ix = lt_ ? iy : ix; iy = lt_ ? ti_ : iy; }
    CSW(v0, v1, p0, p1) CSW(v2, v3, p2, p3) CSW(v0, v2, p0, p2)
    CSW(v1, v3, p1, p3) CSW(v1, v2, p1, p2)
#undef CSW

    // ---- 7 candidate scores (free-sign) ----
    const float A    = (v0 + v1) + (v2 + v3);
    const float base = A - 1.f;                       // id0
    const float r0v = (v0 + v0) - 2.f, r1v = (v1 + v1) - 2.f;
    const float r2v = (v2 + v2) - 2.f, r3v = (v3 + v3) - 2.f;
    const float z0v = ((v0 + v0) + (v0 + v0)) - 6.f;
    const float C1s = base + r0v;
    const float C2s = C1s + r1v;
    const float C3s = C2s + r2v;
    const float C4s = C3s + r3v;
    const float C5s = base + z0v;
    const float C6s = C5s + r1v;

    // parity penalties: candidates' min flip cost is exactly 0.5*v3 (1.5*v3
    // for id4); pattern parity (sum of codes mod 2): odd for ids {1,3,6}.
    const float twov3 = v3 + v3;
    const float pe = qp ? twov3 : 0.f;        // even-parity pattern, qp odd
    const float po = twov3 - pe;              // odd-parity pattern, qp even
    const float p4p = (pe + pe) + pe;         // id4: 6*v3 when qp odd
    const float e0 = base - pe;
    const float e1 = C1s - po;
    const float e2 = C2s - pe;
    const float e3 = C3s - po;
    const float e4 = C4s - p4p;
    const float e5 = C5s - pe;
    const float e6 = C6s - po;

    // ---- top-2 + argmax over 7 (merge second = med3(b1,b2,max(s1,s2))) ----
    const float bA = fmaxf(e0, e1), sA = fminf(e0, e1); const int iA = (e1 > e0) ? 1 : 0;
    const float bB = fmaxf(e2, e3), sB = fminf(e2, e3); const int iB = (e3 > e2) ? 3 : 2;
    const float bC = fmaxf(e4, e5), sC = fminf(e4, e5); const int iC = (e5 > e4) ? 5 : 4;
    const float bAB = fmaxf(bA, bB);
    const float sAB = __builtin_amdgcn_fmed3f(bA, bB, fmaxf(sA, sB));
    const int   iAB = (bB > bA) ? iB : iA;
    const float bCD = fmaxf(bC, e6);
    const float sCD = __builtin_amdgcn_fmed3f(bC, e6, sC);
    const int   iCD = (e6 > bC) ? 6 : iC;
    const float best   = fmaxf(bAB, bCD);
    const float second = __builtin_amdgcn_fmed3f(bAB, bCD, fmaxf(sAB, sCD));
    const int   id     = (bCD > bAB) ? iCD : iAB;

    // ---- certified gap ----
    const float d01 = v0 - v1, d12 = v1 - v2, d23 = v2 - v3;
    const float dadj = fminf(fminf(d01, d12), d23);
    const int flip = (((0x4A >> id) & 1) != qp) ? 1 : 0;   // parity mismatch
    // winner's two smallest flip costs: q1 = (id4?1.5:0.5)*v3, q2 per case
    const float q1 = ((id == 4) ? 1.5f : 0.5f) * v3;
    const float q2 = ((id == 3 || id == 4) ? 1.5f : 0.5f) * v2;
    const float within = flip ? (4.f * (q2 - q1)) : (4.f * (q1 + q2));
    const float gap = fminf(fminf(best - second, dadj + dadj), within);
    const float delta = 8e-6f * (A + 6.f);

    // ---- reconstruct codeword on original coordinates ----
    // codes at sorted positions, scattered through the permutation
    const int cs0 = (id >= 5) ? 2 : ((id >= 1) ? 1 : 0);
    const int cs1 = ((id >= 2 && id <= 4) || id == 6) ? 1 : 0;
    const int cs2 = (id == 3 || id == 4) ? 1 : 0;
    const int cs3 = (id == 4) ? 1 : 0;
    const unsigned mcb = ((unsigned)cs0 << (p0 + p0)) | ((unsigned)cs1 << (p1 + p1))
                       | ((unsigned)cs2 << (p2 + p2)) | ((unsigned)cs3 << (p3 + p3));
    const int c0 = mcb & 3, c1 = (mcb >> 2) & 3, c2 = (mcb >> 4) & 3, c3 = (mcb >> 6) & 3;
    const float m0 = 0.5f + (float)c0, m1 = 0.5f + (float)c1;
    const float m2 = 0.5f + (float)c2, m3 = 0.5f + (float)c3;

    // sign fix: flip exactly coordinate perm[3] on parity mismatch
    const bool n0 = (sg0 != 0) != (flip && p3 == 0);
    const bool n1 = (sg1 != 0) != (flip && p3 == 1);
    const bool n2 = (sg2 != 0) != (flip && p3 == 2);
    const bool n3 = (sg3 != 0) != (flip && p3 == 3);

    float4 g;
    g.x = n0 ? -m0 : m0;
    g.y = n1 ? -m1 : m1;
    g.z = n2 ? -m2 : m2;
    g.w = n3 ? -m3 : m3;

    // ---- reference i8 index from (id, permutation) ----
    // id2 pair {p0,p1}: contains 0 -> i8 = 2*(p0+p1)+1, else complement pair
    // {0,l}: i8 = 2*l = 12-2*(p0+p1).  (verified vs MCP table)
    const int sum01 = p0 + p1;
    const int mn01 = (p0 < p1) ? p0 : p1;
    const int i8_2 = (mn01 == 0) ? (sum01 + sum01 + 1) : (12 - (sum01 + sum01));
    const int i8_6 = 20 + ((p0 - ((p0 > p1) ? 1 : 0)) << 2) + p1;
    int i8v = i8_6;                                   // id6 default
    i8v = (id == 0) ? 0          : i8v;
    i8v = (id == 1) ? (8 + p0)   : i8v;
    i8v = (id == 2) ? i8_2       : i8v;
    i8v = (id == 3) ? (12 + p3)  : i8v;
    i8v = (id == 4) ? 1          : i8v;
    i8v = (id == 5) ? (16 + p0)  : i8v;

    // invert _code3_signs: b7=sign(g0), b6=sign(g1)^b7, b5=sign(g2)^b7
    const int b7 = n0 ? 1 : 0;
    const int b6 = (n1 ? 1 : 0) ^ b7;
    const int b5 = (n2 ? 1 : 0) ^ b7;
    float fidx = (float)(i8v | (b5 << 5) | (b6 << 6) | (b7 << 7));

    if (gap < delta) {
        exact_scan(fx0, fx1, fx2, fx3, sgrid, sgn, &g, &fidx);
    }

    reinterpret_cast<float4*>(out)[i] = g;                 // output 0
    out[(size_t)4 * (size_t)n + (size_t)i] = fidx;         // output 1
}

extern "C" void kernel_launch(void* const* d_in, const int* in_sizes, int n_in,
                              void* d_out, int out_size, void* d_ws, size_t ws_size,
                              hipStream_t stream)
{
    const float* X = (const float*)d_in[0];
    const float* grid = (const float*)d_in[1];
    const float* gnorm = (const float*)d_in[2];
    float* out = (float*)d_out;
    const int n = in_sizes[0] / 4;
    const int blocks = (n + THREADS - 1) / THREADS;
    hipLaunchKernelGGL(d4_fused_kernel, dim3(blocks), dim3(THREADS), 0, stream,
                       X, grid, gnorm, out, n);
}